// Round 7
// baseline (265.001 us; speedup 1.0000x reference)
//
#include <hip/hip_runtime.h>

#define DCH 128
#define T_PART 4096
#define B_MAX 512
#define CAPC 6144
#define CAP_Q 1536

typedef short bf16x8 __attribute__((ext_vector_type(8)));
typedef float f32x4 __attribute__((ext_vector_type(4)));

__device__ inline unsigned short f2bf(float f) {
    unsigned int u = __float_as_uint(f);
    unsigned int r = (u + 0x7fffu + ((u >> 16) & 1u)) >> 16;
    return (unsigned short)r;
}

// ---------------- init: zero cnt+gcount, pack W into MFMA B-frag order -------
// Frag (nt,ks): lane holds B[k=ks*32+(lane>>4)*8+j][n=nt*16+(lane&15)], j=0..7.
__global__ __launch_bounds__(256) void k_init(const float* __restrict__ W,
                                              unsigned short* __restrict__ Wf,
                                              int* __restrict__ cnt,
                                              int* __restrict__ gcount,
                                              int n, int B) {
    int idx = blockIdx.x * 256 + threadIdx.x;
    for (int i = idx; i < n; i += gridDim.x * 256) cnt[i] = 0;
    if (idx < B) gcount[idx] = 0;
    int frag = blockIdx.x * 4 + (threadIdx.x >> 6);
    if (frag < 32) {
        int lane = threadIdx.x & 63;
        int nt = frag >> 2, ks = frag & 3;
        int nn = nt * 16 + (lane & 15);
        int k0 = ks * 32 + ((lane >> 4) * 8);
        unsigned short tmp[8];
#pragma unroll
        for (int j = 0; j < 8; ++j) tmp[j] = f2bf(W[(size_t)(k0 + j) * DCH + nn]);
        *(uint4*)&Wf[((size_t)frag * 64 + lane) * 8] = *(const uint4*)tmp;
    }
}

// ---------------- coarse partition + fused global degree histogram ----------
// Bins edges by dest>>8; one global reservation per bucket per tile +
// contiguous burst writes. cnt[] atomics resolve at L2 (400 KB table).
__global__ __launch_bounds__(512) void k_part(const int* __restrict__ row,
                                              const int* __restrict__ col,
                                              unsigned int* __restrict__ coarse,
                                              int* __restrict__ gcount,
                                              int* __restrict__ cnt,
                                              int E, int B) {
    __shared__ int hist[B_MAX];
    __shared__ int basex[B_MAX];
    __shared__ int curx[B_MAX];
    __shared__ int gb[B_MAX];
    __shared__ int wsum[8];
    __shared__ unsigned int spack[T_PART];
    __shared__ unsigned short sbuck[T_PART];

    int tid = threadIdx.x;
    int wv = tid >> 6, lane = tid & 63;
    int base_e = blockIdx.x * T_PART;
    int tileCnt = min(T_PART, E - base_e);

    hist[tid] = 0;
    __syncthreads();

    int er[8], ec[8];
#pragma unroll
    for (int i = 0; i < 8; ++i) {
        int e = base_e + tid + i * 512;
        if (e < E) {
            er[i] = row[e];
            ec[i] = col[e];
            atomicAdd(&hist[ec[i] >> 8], 1);
            atomicAdd(&cnt[ec[i]], 1);       // global in-degree (for dinv[row])
        } else {
            er[i] = -1;
            ec[i] = 0;
        }
    }
    __syncthreads();

    // exclusive scan over hist[512]: per-wave shfl scan + cross-wave offsets
    int v = hist[tid];
    int x = v;
#pragma unroll
    for (int o = 1; o < 64; o <<= 1) {
        int t = __shfl_up(x, o, 64);
        if (lane >= o) x += t;
    }
    if (lane == 63) wsum[wv] = x;
    __syncthreads();
    int add = 0;
    for (int w = 0; w < wv; ++w) add += wsum[w];
    int excl = x - v + add;
    basex[tid] = excl;
    curx[tid] = excl;
    if (tid < B) gb[tid] = (v > 0) ? atomicAdd(&gcount[tid], v) : 0;
    else gb[tid] = 0;
    __syncthreads();

#pragma unroll
    for (int i = 0; i < 8; ++i) {
        if (er[i] >= 0) {
            int b = ec[i] >> 8;
            int slot = atomicAdd(&curx[b], 1);
            spack[slot] = ((unsigned int)er[i] << 8) | (unsigned int)(ec[i] & 255);
            sbuck[slot] = (unsigned short)b;
        }
    }
    __syncthreads();

    for (int s = tid; s < tileCnt; s += 512) {
        int b = sbuck[s];
        int dst = gb[b] + (s - basex[b]);
        if (dst < CAPC) coarse[(size_t)b * CAPC + dst] = spack[s];
    }
}

// ---------------- y = bf16((x @ W) * rsqrt(deg))  via MFMA ----------------
__global__ __launch_bounds__(256) void k_gemm_mfma(const float* __restrict__ x,
                                                   const unsigned short* __restrict__ Wf,
                                                   const int* __restrict__ cnt,
                                                   unsigned short* __restrict__ y,
                                                   int n) {
    int tid = threadIdx.x;
    int wv = tid >> 6;
    int lane = tid & 63;
    int rowBase = blockIdx.x * 64 + wv * 16;
    int m = rowBase + (lane & 15);
    int mc = (m < n) ? m : (n - 1);
    int kq = (lane >> 4) * 8;

    f32x4 acc[8];
    f32x4 zero = {0.f, 0.f, 0.f, 0.f};
#pragma unroll
    for (int t = 0; t < 8; ++t) acc[t] = zero;

    const bf16x8* wfv = (const bf16x8*)Wf;
#pragma unroll
    for (int ks = 0; ks < 4; ++ks) {
        int kbase = ks * 32 + kq;
        float4 lo = *(const float4*)&x[(size_t)mc * DCH + kbase];
        float4 hi = *(const float4*)&x[(size_t)mc * DCH + kbase + 4];
        bf16x8 a;
        a[0] = (short)f2bf(lo.x); a[1] = (short)f2bf(lo.y);
        a[2] = (short)f2bf(lo.z); a[3] = (short)f2bf(lo.w);
        a[4] = (short)f2bf(hi.x); a[5] = (short)f2bf(hi.y);
        a[6] = (short)f2bf(hi.z); a[7] = (short)f2bf(hi.w);
#pragma unroll
        for (int nt = 0; nt < 8; ++nt) {
            bf16x8 bfr = wfv[(nt * 4 + ks) * 64 + lane];
            acc[nt] = __builtin_amdgcn_mfma_f32_16x16x32_bf16(a, bfr, acc[nt], 0, 0, 0);
        }
    }

    int orow_base = rowBase + ((lane >> 4) * 4);
#pragma unroll
    for (int r = 0; r < 4; ++r) {
        int orow = orow_base + r;
        if (orow < n) {
            float s = rsqrtf((float)(cnt[orow] + 1));
#pragma unroll
            for (int nt = 0; nt < 8; ++nt) {
                y[(size_t)orow * DCH + nt * 16 + (lane & 15)] = f2bf(acc[nt][r] * s);
            }
        }
    }
}

// ---------------- fused grouping + gather-aggregate + bias + ReLU ------------
// Block = quarter-bucket (64 dests), 256 threads, ~6.8 KB LDS (8 blocks/CU).
// Two direct passes over the bucket's coarse entries (no LDS staging, no 4x
// redundancy in the sort phase): hist -> wave scan -> place into lsrc. Then
// each wave aggregates 16 dests with the R4 quarter-wave uint4 gather.
__global__ __launch_bounds__(256) void k_agg(const uint4* __restrict__ y4,
                                             const unsigned int* __restrict__ coarse,
                                             const int* __restrict__ gcount,
                                             const float* __restrict__ b,
                                             float* __restrict__ out, int n) {
    __shared__ int hist_[64], base_[64], cur_[64];
    __shared__ int lsrc[CAP_Q];

    int bkt = blockIdx.x >> 2;
    int qd = blockIdx.x & 3;
    int tid = threadIdx.x;
    int cntb = min(gcount[bkt], CAPC);
    const unsigned int* cbase = &coarse[(size_t)bkt * CAPC];

    if (tid < 64) hist_[tid] = 0;
    __syncthreads();

    for (int s = tid; s < cntb; s += 256) {
        int dlow = cbase[s] & 255;
        if ((dlow >> 6) == qd) atomicAdd(&hist_[dlow & 63], 1);
    }
    __syncthreads();

    if (tid < 64) {               // wave 0: inclusive shfl scan over 64 counts
        int v = hist_[tid];
        int xv = v;
#pragma unroll
        for (int o = 1; o < 64; o <<= 1) {
            int t = __shfl_up(xv, o, 64);
            if (tid >= o) xv += t;
        }
        base_[tid] = xv - v;
        cur_[tid] = xv - v;
    }
    __syncthreads();

    for (int s = tid; s < cntb; s += 256) {
        unsigned int p = cbase[s];
        int dlow = p & 255;
        if ((dlow >> 6) == qd) {
            int slot = atomicAdd(&cur_[dlow & 63], 1);
            if (slot < CAP_Q) lsrc[slot] = (int)(p >> 8);
        }
    }
    __syncthreads();

    int wv = tid >> 6;
    int lane = tid & 63;
    int q = lane >> 4;
    int l16 = lane & 15;

    for (int t = 0; t < 16; ++t) {
        int d6 = wv + 4 * t;
        int i = (bkt << 8) + (qd << 6) + d6;
        if (i >= n) continue;
        int s = base_[d6];
        int deg = hist_[d6];
        int e = s + deg;

        float acc[8];
#pragma unroll
        for (int k = 0; k < 8; ++k) acc[k] = 0.f;

        if (q == 0) {             // self-loop
            uint4 v = y4[(size_t)i * 16 + l16];
            unsigned int p[4] = {v.x, v.y, v.z, v.w};
#pragma unroll
            for (int c = 0; c < 4; ++c) {
                acc[2 * c]     += __uint_as_float(p[c] << 16);
                acc[2 * c + 1] += __uint_as_float(p[c] & 0xffff0000u);
            }
        }

        int j = s;
        for (; j + 8 <= e; j += 8) {
            int s0 = lsrc[j + q];
            int s1 = lsrc[j + 4 + q];
            uint4 v0 = y4[(size_t)s0 * 16 + l16];
            uint4 v1 = y4[(size_t)s1 * 16 + l16];
            unsigned int p0[4] = {v0.x, v0.y, v0.z, v0.w};
            unsigned int p1[4] = {v1.x, v1.y, v1.z, v1.w};
#pragma unroll
            for (int c = 0; c < 4; ++c) {
                acc[2 * c]     += __uint_as_float(p0[c] << 16);
                acc[2 * c + 1] += __uint_as_float(p0[c] & 0xffff0000u);
                acc[2 * c]     += __uint_as_float(p1[c] << 16);
                acc[2 * c + 1] += __uint_as_float(p1[c] & 0xffff0000u);
            }
        }
        for (; j + 4 <= e; j += 4) {
            int s0 = lsrc[j + q];
            uint4 v0 = y4[(size_t)s0 * 16 + l16];
            unsigned int p0[4] = {v0.x, v0.y, v0.z, v0.w};
#pragma unroll
            for (int c = 0; c < 4; ++c) {
                acc[2 * c]     += __uint_as_float(p0[c] << 16);
                acc[2 * c + 1] += __uint_as_float(p0[c] & 0xffff0000u);
            }
        }
        if (j + q < e) {
            int s0 = lsrc[j + q];
            uint4 v0 = y4[(size_t)s0 * 16 + l16];
            unsigned int p0[4] = {v0.x, v0.y, v0.z, v0.w};
#pragma unroll
            for (int c = 0; c < 4; ++c) {
                acc[2 * c]     += __uint_as_float(p0[c] << 16);
                acc[2 * c + 1] += __uint_as_float(p0[c] & 0xffff0000u);
            }
        }

#pragma unroll
        for (int k = 0; k < 8; ++k) {
            acc[k] += __shfl_xor(acc[k], 16, 64);
            acc[k] += __shfl_xor(acc[k], 32, 64);
        }

        if (q == 0) {
            float sc = rsqrtf((float)(deg + 1));
            int c0 = l16 * 8;
            float4 b0 = *(const float4*)&b[c0];
            float4 b1 = *(const float4*)&b[c0 + 4];
            float4 o0, o1;
            o0.x = fmaxf(fmaf(sc, acc[0], b0.x), 0.f);
            o0.y = fmaxf(fmaf(sc, acc[1], b0.y), 0.f);
            o0.z = fmaxf(fmaf(sc, acc[2], b0.z), 0.f);
            o0.w = fmaxf(fmaf(sc, acc[3], b0.w), 0.f);
            o1.x = fmaxf(fmaf(sc, acc[4], b1.x), 0.f);
            o1.y = fmaxf(fmaf(sc, acc[5], b1.y), 0.f);
            o1.z = fmaxf(fmaf(sc, acc[6], b1.z), 0.f);
            o1.w = fmaxf(fmaf(sc, acc[7], b1.w), 0.f);
            float4* orow = (float4*)&out[(size_t)i * DCH + c0];
            orow[0] = o0;
            orow[1] = o1;
        }
    }
}

extern "C" void kernel_launch(void* const* d_in, const int* in_sizes, int n_in,
                              void* d_out, int out_size, void* d_ws, size_t ws_size,
                              hipStream_t stream) {
    const float* x = (const float*)d_in[0];
    const int* ei  = (const int*)d_in[1];
    const float* W = (const float*)d_in[2];
    const float* b = (const float*)d_in[3];
    float* out = (float*)d_out;

    int n = in_sizes[0] / DCH;     // 100000
    int E = in_sizes[1] / 2;       // 1600000
    const int* row = ei;           // sources
    const int* col = ei + E;       // destinations

    int B = (n + 255) / 256;       // 391 coarse buckets

    char* ws = (char*)d_ws;
    size_t o = 0;
    auto alloc = [&](size_t bytes) -> void* {
        o = (o + 255) & ~(size_t)255;
        void* p = ws + o;
        o += bytes;
        return p;
    };
    int* cnt     = (int*)alloc((size_t)n * 4);
    int* gcount  = (int*)alloc((size_t)B * 4);
    unsigned int* coarse = (unsigned int*)alloc((size_t)B * CAPC * 4);  // 9.6 MB
    unsigned short* Wf = (unsigned short*)alloc((size_t)DCH * DCH * 2);
    unsigned short* y  = (unsigned short*)alloc((size_t)n * DCH * 2);   // 25.6 MB

    // 4 dispatches (~7 us gap each measured across R4->R6 deltas)
    int nt = (E + T_PART - 1) / T_PART;  // 391
    k_init<<<128, 256, 0, stream>>>(W, Wf, cnt, gcount, n, B);
    k_part<<<nt, 512, 0, stream>>>(row, col, coarse, gcount, cnt, E, B);
    k_gemm_mfma<<<(n + 63) / 64, 256, 0, stream>>>(x, Wf, cnt, y, n);
    k_agg<<<B * 4, 256, 0, stream>>>((const uint4*)y, coarse, gcount, b, out, n);
}